// Round 5
// baseline (728.194 us; speedup 1.0000x reference)
//
#include <hip/hip_runtime.h>
#include <stdint.h>

// ---------------------------------------------------------------------------
// VQ-VAE quantizer. Coarse search: 256x256 tile, 8 waves (2x4), BK=32,
// ring-3 LDS K-tile slots, phase-sandwich schedule (2 phases/K-tile,
// 16 MFMA per phase, 2 barriers per phase, lgkmcnt(0) discipline),
// counted vmcnt(4) once per K-tile (T4), XOR swizzle (T2), setprio (T5).
// Merge kernel eliminated (rescore reads per-block top-2 directly).
// Sizes: M=B*T=16384, D=1024, K=8192 codes, H=512.
// ---------------------------------------------------------------------------

#define MROWS  16384
#define DDIM   1024
#define KCODES 8192
#define HDIM   512
#define SLOT   32768   // ring slot: A[256][32] 16KB + B[256][32] 16KB

typedef __attribute__((ext_vector_type(4))) float  f32x4;
typedef __attribute__((ext_vector_type(8))) __bf16 bf16x8;

__device__ __forceinline__ unsigned short f2bf(float f) {
  uint32_t b = __float_as_uint(f);
  b += 0x7FFFu + ((b >> 16) & 1u);          // RNE
  return (unsigned short)(b >> 16);
}

__device__ __forceinline__ void gload_lds16(const void* g, void* l) {
  __builtin_amdgcn_global_load_lds(
      (__attribute__((address_space(1))) void*)(uintptr_t)g,
      (__attribute__((address_space(3))) void*)(uint32_t)(uintptr_t)l,
      16, 0, 0);
}

__device__ __forceinline__ float waveReduceSum(float v) {
#pragma unroll
  for (int off = 32; off > 0; off >>= 1) v += __shfl_xor(v, off, 64);
  return v;
}

// ---------------------------------------------------------------------------
// K1: features f32 -> bf16
// ---------------------------------------------------------------------------
__global__ __launch_bounds__(256) void cvt_x_kernel(
    const float* __restrict__ in, unsigned short* __restrict__ o, int n4) {
  const int id = blockIdx.x * 256 + threadIdx.x;
  if (id >= n4) return;
  const float4 v = ((const float4*)in)[id];
  ushort4 u;
  u.x = f2bf(v.x); u.y = f2bf(v.y); u.z = f2bf(v.z); u.w = f2bf(v.w);
  ((ushort4*)o)[id] = u;
}

// ---------------------------------------------------------------------------
// K2: codebook f32 -> bf16 + per-row squared norm cn[k]
// ---------------------------------------------------------------------------
__global__ __launch_bounds__(256) void cvt_cb_cn_kernel(
    const float* __restrict__ cb, unsigned short* __restrict__ o,
    float* __restrict__ cn) {
  __shared__ float wsum[4];
  const int k = blockIdx.x, t = threadIdx.x;
  const float4 v = ((const float4*)(cb + (size_t)k * DDIM))[t];
  ushort4 u;
  u.x = f2bf(v.x); u.y = f2bf(v.y); u.z = f2bf(v.z); u.w = f2bf(v.w);
  ((ushort4*)(o + (size_t)k * DDIM))[t] = u;
  float p = v.x * v.x + v.y * v.y + v.z * v.z + v.w * v.w;
  p = waveReduceSum(p);
  if ((t & 63) == 0) wsum[t >> 6] = p;
  __syncthreads();
  if (t == 0) cn[k] = wsum[0] + wsum[1] + wsum[2] + wsum[3];
}

// ---------------------------------------------------------------------------
// K3: weight transpose f32 [R][C] -> bf16 [C][R]
// ---------------------------------------------------------------------------
__global__ __launch_bounds__(256) void transpose_w_kernel(
    const float* __restrict__ w, unsigned short* __restrict__ wt, int R, int C) {
  const int id = blockIdx.x * 256 + threadIdx.x;
  if (id >= R * C) return;
  const int c = id / R, r = id % R;
  wt[id] = f2bf(w[(size_t)r * C + c]);
}

// ---------------------------------------------------------------------------
// K4: coarse scores = cn[k] - 2 * (xb . cbb[k]).
// 256 rows x 256 codes per block, 8 waves (wm 0..1 x wn 0..3), BK=32.
// Phase A (h0): read A h0 (4 b128) + B (4 b128), stage kt+2 A (2 gload);
//               sandwich; MFMA acc[0..3][*].
// Phase B (h1): read A h1 (4 b128, B in regs), stage kt+2 B (2 gload);
//               vmcnt(4) -> kt+1 landed; sandwich; MFMA acc[4..7][*].
// Ring-3 slots: compute kt (slot p), kt+1 staged, stage kt+2 (slot p+2).
// Fold: per-row top-2 over 256 cols -> cand2[row][nb] (nb 0..31).
// ---------------------------------------------------------------------------
#define PHASE_A(STG)                                                           \
  {                                                                            \
    char* ab = smem + p * SLOT;                                                \
    char* sb = smem + p2 * SLOT;                                               \
    _Pragma("unroll")                                                          \
    for (int mi = 0; mi < 4; ++mi)                                             \
      af[mi] = *reinterpret_cast<const bf16x8*>(ab + aoff0 + mi * 1024);       \
    _Pragma("unroll")                                                          \
    for (int ni = 0; ni < 4; ++ni)                                             \
      bv[ni] = *reinterpret_cast<const bf16x8*>(ab + boff0 + ni * 1024);       \
    if (STG) {                                                                 \
      gload_lds16(aS0, sb + dstA0);                                            \
      gload_lds16(aS1, sb + dstA1);                                            \
    }                                                                          \
    __builtin_amdgcn_sched_barrier(0);                                         \
    __builtin_amdgcn_s_barrier();                                              \
    asm volatile("s_waitcnt lgkmcnt(0)" ::: "memory");                         \
    __builtin_amdgcn_sched_barrier(0);                                         \
    __builtin_amdgcn_s_setprio(1);                                             \
    _Pragma("unroll")                                                          \
    for (int mi = 0; mi < 4; ++mi)                                             \
      _Pragma("unroll")                                                        \
      for (int ni = 0; ni < 4; ++ni)                                           \
        acc[mi][ni] = __builtin_amdgcn_mfma_f32_16x16x32_bf16(                 \
            af[mi], bv[ni], acc[mi][ni], 0, 0, 0);                             \
    __builtin_amdgcn_s_setprio(0);                                             \
    __builtin_amdgcn_sched_barrier(0);                                         \
    __builtin_amdgcn_s_barrier();                                              \
  }

#define PHASE_B(STG, VM4)                                                      \
  {                                                                            \
    char* ab = smem + p * SLOT;                                                \
    char* sb = smem + p2 * SLOT;                                               \
    _Pragma("unroll")                                                          \
    for (int mi = 0; mi < 4; ++mi)                                             \
      af[mi] = *reinterpret_cast<const bf16x8*>(ab + aoff0 + 4096 + mi * 1024);\
    if (STG) {                                                                 \
      gload_lds16(bS0, sb + dstB0);                                            \
      gload_lds16(bS1, sb + dstB1);                                            \
    }                                                                          \
    __builtin_amdgcn_sched_barrier(0);                                         \
    if (VM4) { asm volatile("s_waitcnt vmcnt(4)" ::: "memory"); }              \
    else     { asm volatile("s_waitcnt vmcnt(0)" ::: "memory"); }              \
    __builtin_amdgcn_s_barrier();                                              \
    asm volatile("s_waitcnt lgkmcnt(0)" ::: "memory");                         \
    __builtin_amdgcn_sched_barrier(0);                                         \
    __builtin_amdgcn_s_setprio(1);                                             \
    _Pragma("unroll")                                                          \
    for (int mi = 0; mi < 4; ++mi)                                             \
      _Pragma("unroll")                                                        \
      for (int ni = 0; ni < 4; ++ni)                                           \
        acc[mi + 4][ni] = __builtin_amdgcn_mfma_f32_16x16x32_bf16(             \
            af[mi], bv[ni], acc[mi + 4][ni], 0, 0, 0);                         \
    __builtin_amdgcn_s_setprio(0);                                             \
    __builtin_amdgcn_sched_barrier(0);                                         \
    __builtin_amdgcn_s_barrier();                                              \
  }

__global__ __launch_bounds__(512, 1) void coarse_kernel(
    const unsigned short* __restrict__ xb,   // [MROWS][DDIM] bf16
    const unsigned short* __restrict__ cbb,  // [KCODES][DDIM] bf16
    const float* __restrict__ cn,            // [KCODES]
    uint32_t* __restrict__ cand2)            // [MROWS][32][4]
{
  __shared__ char smem[98304];   // 3 x SLOT; fold scratch aliased after loop

  const int tid = threadIdx.x;
  const int l = tid & 63, w = tid >> 6;
  const int lr = l & 15, lg = l >> 4;
  const int wm = w >> 2, wn = w & 3;

  // bijective XCD swizzle (nwg = 2048 = 8 * 256)
  const int bid = blockIdx.x;
  const int swz = (bid & 7) * 256 + (bid >> 3);
  const int mb = swz >> 5, nb = swz & 31;
  const int r0 = mb * 256, c0 = nb * 256;

  // staging: per round (8KB), dest D = tid*16; row = round*128 + (tid>>2),
  // col elems = (((tid&3)*16) ^ (((tid>>3)&3)<<4)) >> 1  (inverse of read swz)
  const int srow = tid >> 2;                                     // 0..127
  const int scol = (((tid & 3) * 16) ^ (((tid >> 3) & 3) << 4)) >> 1;

  const unsigned short* aS0 = xb + (size_t)(r0 + srow) * DDIM + scol;
  const unsigned short* aS1 = aS0 + (size_t)128 * DDIM;
  const unsigned short* bS0 = cbb + (size_t)(c0 + srow) * DDIM + scol;
  const unsigned short* bS1 = bS0 + (size_t)128 * DDIM;

  const int dstA0 = tid * 16,          dstA1 = 8192 + tid * 16;
  const int dstB0 = 16384 + tid * 16,  dstB1 = 24576 + tid * 16;

  // fragment ds_read byte offsets (swizzle bits 4-5; uniform over mi/ni)
  const int xorb = ((lr >> 1) & 3) << 4;
  const int aoff0 = (wm * 128 + lr) * 64 + ((lg * 16) ^ xorb);
  const int boff0 = 16384 + (wn * 64 + lr) * 64 + ((lg * 16) ^ xorb);

  f32x4 acc[8][4];
#pragma unroll
  for (int mi = 0; mi < 8; ++mi)
#pragma unroll
    for (int ni = 0; ni < 4; ++ni) acc[mi][ni] = 0.0f;

  // prologue: stage kt0 -> slot0, kt1 -> slot1 (8 loads)
  gload_lds16(aS0, smem + dstA0);
  gload_lds16(aS1, smem + dstA1);
  gload_lds16(bS0, smem + dstB0);
  gload_lds16(bS1, smem + dstB1);
  gload_lds16(aS0 + 32, smem + SLOT + dstA0);
  gload_lds16(aS1 + 32, smem + SLOT + dstA1);
  gload_lds16(bS0 + 32, smem + SLOT + dstB0);
  gload_lds16(bS1 + 32, smem + SLOT + dstB1);
  aS0 += 64; aS1 += 64; bS0 += 64; bS1 += 64;   // stage target: kt+2

  asm volatile("s_waitcnt vmcnt(4)" ::: "memory");  // kt0 landed
  __builtin_amdgcn_s_barrier();

  int p = 0;
#pragma unroll 1
  for (int kt = 0; kt < 30; ++kt) {
    const int p2 = (p == 0) ? 2 : p - 1;  // (p+2)%3
    bf16x8 af[4], bv[4];
    PHASE_A(1)
    PHASE_B(1, 1)
    aS0 += 32; aS1 += 32; bS0 += 32; bS1 += 32;
    p = (p == 2) ? 0 : p + 1;
  }
  {  // kt = 30: no staging; vmcnt(0) -> kt31 landed
    const int p2 = (p == 0) ? 2 : p - 1;
    bf16x8 af[4], bv[4];
    PHASE_A(0)
    PHASE_B(0, 0)
    p = (p == 2) ? 0 : p + 1;
  }
  {  // kt = 31
    const int p2 = (p == 0) ? 2 : p - 1;
    bf16x8 af[4], bv[4];
    PHASE_A(0)
    PHASE_B(0, 0)
  }

  __syncthreads();   // ring dead; smem reused as fold scratch
  uint2* mrg = (uint2*)smem;   // [256 rows][4 wn][2 slots] = 16KB

  float cnv[4];
#pragma unroll
  for (int ni = 0; ni < 4; ++ni) cnv[ni] = cn[c0 + wn * 64 + ni * 16 + lr];

#pragma unroll
  for (int mi = 0; mi < 8; ++mi) {
#pragma unroll
    for (int r = 0; r < 4; ++r) {
      float s1 = __builtin_inff(), s2 = __builtin_inff();
      int   i1 = KCODES, i2 = KCODES;
#pragma unroll
      for (int ni = 0; ni < 4; ++ni) {
        const float s = fmaf(-2.0f, acc[mi][ni][r], cnv[ni]);
        const int col = c0 + wn * 64 + ni * 16 + lr;
        const bool lt1 = s < s1;
        const bool lt2 = s < s2;
        s2 = lt1 ? s1 : (lt2 ? s   : s2);
        i2 = lt1 ? i1 : (lt2 ? col : i2);
        s1 = lt1 ? s   : s1;
        i1 = lt1 ? col : i1;
      }
      // butterfly over the 16 lanes sharing this row
#pragma unroll
      for (int off = 1; off < 16; off <<= 1) {
        const float t1 = __shfl_xor(s1, off, 64);
        const int   j1 = __shfl_xor(i1, off, 64);
        const float t2 = __shfl_xor(s2, off, 64);
        const int   j2 = __shfl_xor(i2, off, 64);
        const bool c1 = (t1 < s1) || (t1 == s1 && j1 < i1);
        const float w1s = c1 ? t1 : s1; const int w1i = c1 ? j1 : i1;
        const float l1s = c1 ? s1 : t1; const int l1i = c1 ? i1 : j1;
        const bool c2 = (t2 < s2) || (t2 == s2 && j2 < i2);
        const float m2s = c2 ? t2 : s2; const int m2i = c2 ? j2 : i2;
        const bool c3 = (m2s < l1s) || (m2s == l1s && m2i < l1i);
        s2 = c3 ? m2s : l1s; i2 = c3 ? m2i : l1i;
        s1 = w1s;            i1 = w1i;
      }
      if (lr == 0) {
        // row within block: h-half from mi>=4, then 16-row tile
        const int row = wm * 128 + ((mi >> 2) * 64) + (mi & 3) * 16 + lg * 4 + r;
        uint2 e0; e0.x = __float_as_uint(s1); e0.y = (uint32_t)i1;
        uint2 e1; e1.x = __float_as_uint(s2); e1.y = (uint32_t)i2;
        mrg[(row * 4 + wn) * 2 + 0] = e0;
        mrg[(row * 4 + wn) * 2 + 1] = e1;
      }
    }
  }
  __syncthreads();

  if (tid < 256) {
    const int row = tid;
    float s1 = __builtin_inff(), s2 = __builtin_inff();
    int   i1 = KCODES, i2 = KCODES;
    const uint2* mp = mrg + row * 8;
#pragma unroll
    for (int t = 0; t < 8; ++t) {
      const float s = __uint_as_float(mp[t].x);
      const int   i = (int)mp[t].y;
      if (s < s1 || (s == s1 && i < i1)) { s2 = s1; i2 = i1; s1 = s; i1 = i; }
      else if (s < s2 || (s == s2 && i < i2)) { s2 = s; i2 = i; }
    }
    uint4 o;
    o.x = __float_as_uint(s1); o.y = (uint32_t)i1;
    o.z = __float_as_uint(s2); o.w = (uint32_t)i2;
    *((uint4*)(cand2 + ((size_t)(r0 + row) * 32 + nb) * 4)) = o;
  }
}

// ---------------------------------------------------------------------------
// K5: merged top-select + exact fp32 rescore. One wave per row; lane l holds
// 1 of 64 (score,idx) pairs. Fast path: exactly one candidate within
// min+2.5 margin (typical). Slow path: fp32-rescore every in-margin code.
// ---------------------------------------------------------------------------
__global__ __launch_bounds__(256) void rescore_kernel(
    const float* __restrict__ x, const float* __restrict__ cb,
    const uint32_t* __restrict__ cand2, int* __restrict__ idx_ws,
    float* __restrict__ out) {
  const int row = blockIdx.x * 4 + (threadIdx.x >> 6);
  const int l = threadIdx.x & 63;
  if (row == 0 && l == 0) out[(size_t)MROWS * DDIM + MROWS] = 0.0f;

  const uint2 pr = ((const uint2*)(cand2 + (size_t)row * 128))[l];
  const float s = __uint_as_float(pr.x);
  const int   ci = (int)pr.y;

  // 64-lane (score, idx) min-reduce with first-index tie-break
  float bs = s; int bi = ci;
#pragma unroll
  for (int off = 1; off < 64; off <<= 1) {
    const float os = __shfl_xor(bs, off, 64);
    const int   oi = __shfl_xor(bi, off, 64);
    if (os < bs || (os == bs && oi < bi)) { bs = os; bi = oi; }
  }
  const float thr = bs + 2.5f;
  unsigned long long m = __ballot(s <= thr);

  if (__popcll(m) == 1) {
    if (l == 0) {
      idx_ws[row] = bi;
      out[(size_t)MROWS * DDIM + row] = (float)bi;
    }
    return;
  }

  // slow path (rare): exact fp32 rescore of each in-margin candidate
  const float4* x4 = (const float4*)(x + (size_t)row * DDIM);
  float4 xv[4];
#pragma unroll
  for (int i = 0; i < 4; ++i) xv[i] = x4[i * 64 + l];

  float bestS = __builtin_inff(); int bestI = KCODES;
  while (m) {
    const int b = __builtin_ctzll(m);
    m &= m - 1;
    const int code = __shfl(ci, b, 64);
    const float4* c4 = (const float4*)(cb + (size_t)code * DDIM);
    float dot = 0.f, nn = 0.f;
#pragma unroll
    for (int i = 0; i < 4; ++i) {
      const float4 cv = c4[i * 64 + l];
      dot = fmaf(xv[i].x, cv.x, dot); dot = fmaf(xv[i].y, cv.y, dot);
      dot = fmaf(xv[i].z, cv.z, dot); dot = fmaf(xv[i].w, cv.w, dot);
      nn  = fmaf(cv.x, cv.x, nn);     nn  = fmaf(cv.y, cv.y, nn);
      nn  = fmaf(cv.z, cv.z, nn);     nn  = fmaf(cv.w, cv.w, nn);
    }
#pragma unroll
    for (int off = 32; off > 0; off >>= 1) {
      dot += __shfl_xor(dot, off, 64);
      nn  += __shfl_xor(nn,  off, 64);
    }
    const float sc = nn - 2.0f * dot;
    if (sc < bestS || (sc == bestS && code < bestI)) { bestS = sc; bestI = code; }
  }
  if (l == 0) {
    idx_ws[row] = bestI;
    out[(size_t)MROWS * DDIM + row] = (float)bestI;
  }
}

// ---------------------------------------------------------------------------
// K6/K7: bf16 GEMM C = A[M][K] * B[N][K]^T (+bias). EPI==1: relu->bf16.
// EPI==2: f32 store.
// ---------------------------------------------------------------------------
template <int EPI>
__global__ __launch_bounds__(256) void gemm_bt_kernel(
    const unsigned short* __restrict__ A, const unsigned short* __restrict__ B,
    const float* __restrict__ bias, void* __restrict__ outp,
    int Nsize, int Kred, int nblk) {
  __shared__ unsigned short As[128 * 32];
  __shared__ unsigned short Bs[128 * 32];
  const int tid = threadIdx.x;
  const int l = tid & 63, w = tid >> 6;
  const int lr = l & 15, lg = l >> 4;
  const int wm = w >> 1, wn = w & 1;
  const int mb = blockIdx.x / nblk, nb = blockIdx.x % nblk;
  const int r0 = mb * 128, c0 = nb * 128;
  const int prow = tid >> 2, pcol = (tid & 3) * 8;

  f32x4 acc[4][4];
#pragma unroll
  for (int mi = 0; mi < 4; ++mi)
#pragma unroll
    for (int ni = 0; ni < 4; ++ni) acc[mi][ni] = 0.0f;

  const size_t aoff0 = (size_t)(r0 + prow) * Kred + pcol;
  const size_t aoff1 = aoff0 + (size_t)64 * Kred;
  const size_t boff0 = (size_t)(c0 + prow) * Kred + pcol;
  const size_t boff1 = boff0 + (size_t)64 * Kred;

  const int nks = Kred >> 5;
  for (int ks = 0; ks < nks; ++ks) {
    const int k0 = ks * 32;
    gload_lds16(A + aoff0 + k0, &As[tid * 8]);
    gload_lds16(A + aoff1 + k0, &As[2048 + tid * 8]);
    gload_lds16(B + boff0 + k0, &Bs[tid * 8]);
    gload_lds16(B + boff1 + k0, &Bs[2048 + tid * 8]);
    __syncthreads();

    bf16x8 af[4], bfv[4];
#pragma unroll
    for (int mi = 0; mi < 4; ++mi)
      af[mi] = *reinterpret_cast<const bf16x8*>(
          &As[(wm * 64 + mi * 16 + lr) * 32 + lg * 8]);
#pragma unroll
    for (int ni = 0; ni < 4; ++ni)
      bfv[ni] = *reinterpret_cast<const bf16x8*>(
          &Bs[(wn * 64 + ni * 16 + lr) * 32 + lg * 8]);
#pragma unroll
    for (int mi = 0; mi < 4; ++mi)
#pragma unroll
      for (int ni = 0; ni < 4; ++ni)
        acc[mi][ni] = __builtin_amdgcn_mfma_f32_16x16x32_bf16(
            af[mi], bfv[ni], acc[mi][ni], 0, 0, 0);
    __syncthreads();
  }

#pragma unroll
  for (int ni = 0; ni < 4; ++ni) {
    const int col = c0 + wn * 64 + ni * 16 + lr;
    const float bv = bias[col];
#pragma unroll
    for (int mi = 0; mi < 4; ++mi) {
#pragma unroll
      for (int r = 0; r < 4; ++r) {
        const int row = r0 + wm * 64 + mi * 16 + lg * 4 + r;
        const float v = acc[mi][ni][r] + bv;
        if (EPI == 1) {
          ((unsigned short*)outp)[(size_t)row * Nsize + col] =
              f2bf(fmaxf(v, 0.0f));
        } else {
          ((float*)outp)[(size_t)row * Nsize + col] = v;
        }
      }
    }
  }
}

// ---------------------------------------------------------------------------
// K8: recon[row] = dec[idx[row]] gather-write + fused commitment loss.
// ---------------------------------------------------------------------------
__global__ __launch_bounds__(256) void epilogue_kernel(
    const float* __restrict__ x, const float* __restrict__ cb,
    const float* __restrict__ dec, const int* __restrict__ idx_ws,
    float* __restrict__ out) {
  __shared__ float wsum[4];
  const int r = blockIdx.x, t = threadIdx.x;
  const int code = idx_ws[r];
  const float4 dv = ((const float4*)(dec + (size_t)code * DDIM))[t];
  ((float4*)(out + (size_t)r * DDIM))[t] = dv;
  const float4 xv = ((const float4*)(x + (size_t)r * DDIM))[t];
  const float4 cv = ((const float4*)(cb + (size_t)code * DDIM))[t];
  const float ex = xv.x - cv.x, ey = xv.y - cv.y;
  const float ez = xv.z - cv.z, ew = xv.w - cv.w;
  float pr = ex * ex + ey * ey + ez * ez + ew * ew;
  pr = waveReduceSum(pr);
  if ((t & 63) == 0) wsum[t >> 6] = pr;
  __syncthreads();
  if (t == 0) {
    const float total = wsum[0] + wsum[1] + wsum[2] + wsum[3];
    atomicAdd(out + (size_t)MROWS * DDIM + MROWS, total * (0.25f / 16777216.0f));
  }
}

// ---------------------------------------------------------------------------
extern "C" void kernel_launch(void* const* d_in, const int* in_sizes, int n_in,
                              void* d_out, int out_size, void* d_ws,
                              size_t ws_size, hipStream_t stream) {
  const float* features = (const float*)d_in[0];  // [8,2048,1024]
  const float* codebook = (const float*)d_in[1];  // [8192,1024]
  const float* w1 = (const float*)d_in[2];        // [1024,512]
  const float* b1 = (const float*)d_in[3];        // [512]
  const float* w2 = (const float*)d_in[4];        // [512,1024]
  const float* b2 = (const float*)d_in[5];        // [1024]
  float* out = (float*)d_out;
  char* ws = (char*)d_ws;

  unsigned short* xb  = (unsigned short*)(ws + 0);         // 33,554,432
  unsigned short* cbb = (unsigned short*)(ws + 33554432);  // 16,777,216
  float*          cn  = (float*)(ws + 50331648);           //     32,768
  unsigned short* w1t = (unsigned short*)(ws + 50364416);  //  1,048,576
  unsigned short* w2t = (unsigned short*)(ws + 51412992);  //  1,048,576
  unsigned short* hb  = (unsigned short*)(ws + 52461568);  //  8,388,608
  float*          dec = (float*)(ws + 60850176);           // 33,554,432
  int*            idxw = (int*)(ws + 95453184);            //     65,536
  // cand2 (8 MB) aliases dec: consumed by rescore BEFORE gemm<2> writes dec
  // (stream-ordered -> safe).
  uint32_t*       cand2 = (uint32_t*)(ws + 60850176);

  cvt_x_kernel<<<16384, 256, 0, stream>>>(features, xb, MROWS * DDIM / 4);
  cvt_cb_cn_kernel<<<KCODES, 256, 0, stream>>>(codebook, cbb, cn);
  transpose_w_kernel<<<2048, 256, 0, stream>>>(w1, w1t, DDIM, HDIM);
  transpose_w_kernel<<<2048, 256, 0, stream>>>(w2, w2t, HDIM, DDIM);

  coarse_kernel<<<(MROWS / 256) * (KCODES / 256), 512, 0, stream>>>(
      xb, cbb, cn, cand2);
  rescore_kernel<<<MROWS / 4, 256, 0, stream>>>(features, codebook, cand2,
                                                idxw, out);

  // decode the codebook (8192 rows), then recon = dec[idx]
  gemm_bt_kernel<1><<<64 * (HDIM / 128), 256, 0, stream>>>(
      cbb, w1t, b1, hb, HDIM, DDIM, HDIM / 128);
  gemm_bt_kernel<2><<<64 * (DDIM / 128), 256, 0, stream>>>(
      hb, w2t, b2, dec, DDIM, HDIM, DDIM / 128);

  epilogue_kernel<<<MROWS, 256, 0, stream>>>(features, codebook, dec, idxw, out);
}

// Round 7
// 674.391 us; speedup vs baseline: 1.0798x; 1.0798x over previous
//
#include <hip/hip_runtime.h>
#include <hip/hip_fp8.h>
#include <stdint.h>

// ---------------------------------------------------------------------------
// VQ-VAE quantizer. Coarse search: MX-fp8 (e4m3, scales=1.0)
// mfma_scale_f32_16x16x128_f8f6f4, 256x256 tile, 8 waves (2x4), BK=128,
// LDS double-buffer 2x64KB. R7: sched_barrier(0) fences pin every
// global_load_lds issue between the retiring __syncthreads and the next
// ds_reads (R6 raced on replay without them -- compiler motion of the
// unmodeled LDS-write side effect).
// Sizes: M=B*T=16384, D=1024, K=8192 codes, H=512.
// ---------------------------------------------------------------------------

#define MROWS  16384
#define DDIM   1024
#define KCODES 8192
#define HDIM   512

typedef __attribute__((ext_vector_type(4))) float  f32x4;
typedef __attribute__((ext_vector_type(8))) __bf16 bf16x8;
typedef __attribute__((ext_vector_type(4))) int    i32x4;
typedef __attribute__((ext_vector_type(8))) int    i32x8;

__device__ __forceinline__ unsigned short f2bf(float f) {
  uint32_t b = __float_as_uint(f);
  b += 0x7FFFu + ((b >> 16) & 1u);          // RNE
  return (unsigned short)(b >> 16);
}

__device__ __forceinline__ uint32_t f2fp8(float f) {
  return (uint32_t)__hip_fp8_e4m3(f).__x;   // OCP e4m3fn, saturating
}

__device__ __forceinline__ void gload_lds16(const void* g, void* l) {
  __builtin_amdgcn_global_load_lds(
      (__attribute__((address_space(1))) void*)(uintptr_t)g,
      (__attribute__((address_space(3))) void*)(uint32_t)(uintptr_t)l,
      16, 0, 0);
}

__device__ __forceinline__ f32x4 mfma_mx(i32x8 a, i32x8 b, f32x4 c) {
  // cbsz=0 (A=fp8 e4m3), blgp=0 (B=fp8); scales: every byte 127 -> 2^0
  return __builtin_amdgcn_mfma_scale_f32_16x16x128_f8f6f4(
      a, b, c, 0, 0, 0, 0x7F7F7F7F, 0, 0x7F7F7F7F);
}

__device__ __forceinline__ float waveReduceSum(float v) {
#pragma unroll
  for (int off = 32; off > 0; off >>= 1) v += __shfl_xor(v, off, 64);
  return v;
}

// ---------------------------------------------------------------------------
// K1: features f32 -> fp8 e4m3 (8 elems/thread)
// ---------------------------------------------------------------------------
__global__ __launch_bounds__(256) void cvt_x_kernel(
    const float* __restrict__ in, uint8_t* __restrict__ q8, int n8) {
  const int id = blockIdx.x * 256 + threadIdx.x;
  if (id >= n8) return;
  const float4 v0 = ((const float4*)in)[id * 2];
  const float4 v1 = ((const float4*)in)[id * 2 + 1];
  uint32_t a = f2fp8(v0.x) | (f2fp8(v0.y) << 8) | (f2fp8(v0.z) << 16) |
               (f2fp8(v0.w) << 24);
  uint32_t b = f2fp8(v1.x) | (f2fp8(v1.y) << 8) | (f2fp8(v1.z) << 16) |
               (f2fp8(v1.w) << 24);
  uint2 u; u.x = a; u.y = b;
  ((uint2*)q8)[id] = u;
}

// ---------------------------------------------------------------------------
// K2: codebook f32 -> {bf16 (decoder GEMM), fp8 (coarse)} + norm cn[k]
// ---------------------------------------------------------------------------
__global__ __launch_bounds__(256) void cvt_cb_cn_kernel(
    const float* __restrict__ cb, unsigned short* __restrict__ obf,
    uint8_t* __restrict__ q8, float* __restrict__ cn) {
  __shared__ float wsum[4];
  const int k = blockIdx.x, t = threadIdx.x;
  const float4 v = ((const float4*)(cb + (size_t)k * DDIM))[t];
  ushort4 u;
  u.x = f2bf(v.x); u.y = f2bf(v.y); u.z = f2bf(v.z); u.w = f2bf(v.w);
  ((ushort4*)(obf + (size_t)k * DDIM))[t] = u;
  const uint32_t p8 = f2fp8(v.x) | (f2fp8(v.y) << 8) | (f2fp8(v.z) << 16) |
                      (f2fp8(v.w) << 24);
  ((uint32_t*)(q8 + (size_t)k * DDIM))[t] = p8;
  float p = v.x * v.x + v.y * v.y + v.z * v.z + v.w * v.w;
  p = waveReduceSum(p);
  if ((t & 63) == 0) wsum[t >> 6] = p;
  __syncthreads();
  if (t == 0) cn[k] = wsum[0] + wsum[1] + wsum[2] + wsum[3];
}

// ---------------------------------------------------------------------------
// K3: weight transpose f32 [R][C] -> bf16 [C][R]
// ---------------------------------------------------------------------------
__global__ __launch_bounds__(256) void transpose_w_kernel(
    const float* __restrict__ w, unsigned short* __restrict__ wt, int R, int C) {
  const int id = blockIdx.x * 256 + threadIdx.x;
  if (id >= R * C) return;
  const int c = id / R, r = id % R;
  wt[id] = f2bf(w[(size_t)r * C + c]);
}

// ---------------------------------------------------------------------------
// K4: coarse scores = cn[k] - 2 * (xq . cq) via MX-fp8 MFMA (K=128).
// 256 rows x 256 codes per block, 8 waves (wm 0..1 x wn 0..3), 8 K-tiles.
// LDS buf: A[256][128B] 32KB + B[256][128B] 32KB, XOR swizzle
// byte ^= ((row&7)<<4), pre-swizzled global source (both-sides, rule 21).
// STAGE(kt+2) issued right after the barrier retiring kt, PINNED with
// sched_barrier(0) on both sides (the R6 race fix).
// Fold: per-row top-2 over 256 cols -> cand2[row][nb] (nb 0..31).
// ---------------------------------------------------------------------------
__global__ __launch_bounds__(512, 2) void coarse_kernel(
    const uint8_t* __restrict__ xq,   // [MROWS][DDIM] fp8
    const uint8_t* __restrict__ cq,   // [KCODES][DDIM] fp8
    const float* __restrict__ cn,     // [KCODES]
    uint32_t* __restrict__ cand2)     // [MROWS][32][4]
{
  __shared__ char smem[131072];   // 2 x (A 32KB + B 32KB); fold scratch aliased

  const int tid = threadIdx.x;
  const int l = tid & 63, w = tid >> 6;
  const int lr = l & 15, lg = l >> 4;
  const int wm = w >> 2, wn = w & 3;

  // bijective XCD swizzle (nwg = 2048 = 8 * 256)
  const int bid = blockIdx.x;
  const int swz = (bid & 7) * 256 + (bid >> 3);
  const int mb = swz >> 5, nb = swz & 31;
  const int r0 = mb * 256, c0 = nb * 256;

  // staging: linear LDS dest tid*16 (+j*8192); that chunk holds
  // global row = tid>>3 (+j*64), col byte = ((tid&7)*16) ^ ((row&7)<<4)
  const int srow = tid >> 3;                                   // 0..63
  const int scolb = ((tid & 7) * 16) ^ ((srow & 7) << 4);
  const uint8_t* aSrc = xq + (size_t)(r0 + srow) * DDIM + scolb;
  const uint8_t* bSrc = cq + (size_t)(c0 + srow) * DDIM + scolb;
  const int dBase = tid * 16;

  // fragment ds_read offsets. row&7 == lr&7 (row = multiple-of-16 + lr)
  const int sxor = (lr & 7) << 4;
  const int kLo = (lg * 32) ^ sxor;
  const int kHi = (lg * 32 + 16) ^ sxor;
  const int aRow = (wm * 128 + lr) * 128;           // + mi*2048
  const int bRow = 32768 + (wn * 64 + lr) * 128;    // + ni*2048

#define STAGE(KT, BUF)                                                        \
  {                                                                           \
    char* sb = smem + (BUF) * 65536;                                          \
    _Pragma("unroll")                                                         \
    for (int j = 0; j < 4; ++j)                                               \
      gload_lds16(aSrc + (size_t)j * 65536 + (KT) * 128,                      \
                  sb + dBase + j * 8192);                                     \
    _Pragma("unroll")                                                         \
    for (int j = 0; j < 4; ++j)                                               \
      gload_lds16(bSrc + (size_t)j * 65536 + (KT) * 128,                      \
                  sb + 32768 + dBase + j * 8192);                             \
  }

#define LDFRAG(dst, off)                                                      \
  {                                                                           \
    i32x4 _lo = *(const i32x4*)(ab + (off) + kLo);                            \
    i32x4 _hi = *(const i32x4*)(ab + (off) + kHi);                            \
    dst = __builtin_shufflevector(_lo, _hi, 0, 1, 2, 3, 4, 5, 6, 7);          \
  }

  f32x4 acc[8][4];
#pragma unroll
  for (int mi = 0; mi < 8; ++mi)
#pragma unroll
    for (int ni = 0; ni < 4; ++ni) acc[mi][ni] = 0.0f;

  // prologue: stage kt0 -> buf0, kt1 -> buf1 (pinned)
  __builtin_amdgcn_sched_barrier(0);
  STAGE(0, 0)
  STAGE(1, 1)
  __builtin_amdgcn_sched_barrier(0);
  __syncthreads();                         // drains vmcnt(0): kt0+kt1 landed

#pragma unroll 1
  for (int kt = 0; kt < 8; ++kt) {
    const char* ab = smem + (kt & 1) * 65536;
    i32x8 bf[4], af[4];
#pragma unroll
    for (int ni = 0; ni < 4; ++ni) LDFRAG(bf[ni], bRow + ni * 2048)
#pragma unroll
    for (int mi = 0; mi < 4; ++mi) LDFRAG(af[mi], aRow + mi * 2048)
    __builtin_amdgcn_s_setprio(1);
#pragma unroll
    for (int mi = 0; mi < 4; ++mi)
#pragma unroll
      for (int ni = 0; ni < 4; ++ni)
        acc[mi][ni] = mfma_mx(af[mi], bf[ni], acc[mi][ni]);
    __builtin_amdgcn_s_setprio(0);
#pragma unroll
    for (int mi = 0; mi < 4; ++mi) LDFRAG(af[mi], aRow + (mi + 4) * 2048)
    __builtin_amdgcn_s_setprio(1);
#pragma unroll
    for (int mi = 0; mi < 4; ++mi)
#pragma unroll
      for (int ni = 0; ni < 4; ++ni)
        acc[mi + 4][ni] = mfma_mx(af[mi], bf[ni], acc[mi + 4][ni]);
    __builtin_amdgcn_s_setprio(0);
    __builtin_amdgcn_sched_barrier(0);     // no ds_read may sink below barrier
    __syncthreads();                       // kt retired (vmcnt+lgkm drained)
    __builtin_amdgcn_sched_barrier(0);     // STAGE may not hoist above barrier
    if (kt < 6) STAGE(kt + 2, kt & 1)
    __builtin_amdgcn_sched_barrier(0);     // next reads may not hoist above
  }

  // ------------------ fold: per-row top-2 over this block's 256 cols ------
  uint2* mrg = (uint2*)smem;   // [256 rows][4 wn][2 slots] = 16KB

  float cnv[4];
#pragma unroll
  for (int ni = 0; ni < 4; ++ni) cnv[ni] = cn[c0 + wn * 64 + ni * 16 + lr];

#pragma unroll
  for (int mi = 0; mi < 8; ++mi) {
#pragma unroll
    for (int r = 0; r < 4; ++r) {
      float s1 = __builtin_inff(), s2 = __builtin_inff();
      int   i1 = KCODES, i2 = KCODES;
#pragma unroll
      for (int ni = 0; ni < 4; ++ni) {
        const float s = fmaf(-2.0f, acc[mi][ni][r], cnv[ni]);
        const int col = c0 + wn * 64 + ni * 16 + lr;
        const bool lt1 = s < s1;
        const bool lt2 = s < s2;
        s2 = lt1 ? s1 : (lt2 ? s   : s2);
        i2 = lt1 ? i1 : (lt2 ? col : i2);
        s1 = lt1 ? s   : s1;
        i1 = lt1 ? col : i1;
      }
#pragma unroll
      for (int off = 1; off < 16; off <<= 1) {
        const float t1 = __shfl_xor(s1, off, 64);
        const int   j1 = __shfl_xor(i1, off, 64);
        const float t2 = __shfl_xor(s2, off, 64);
        const int   j2 = __shfl_xor(i2, off, 64);
        const bool c1 = (t1 < s1) || (t1 == s1 && j1 < i1);
        const float w1s = c1 ? t1 : s1; const int w1i = c1 ? j1 : i1;
        const float l1s = c1 ? s1 : t1; const int l1i = c1 ? i1 : j1;
        const bool c2 = (t2 < s2) || (t2 == s2 && j2 < i2);
        const float m2s = c2 ? t2 : s2; const int m2i = c2 ? j2 : i2;
        const bool c3 = (m2s < l1s) || (m2s == l1s && m2i < l1i);
        s2 = c3 ? m2s : l1s; i2 = c3 ? m2i : l1i;
        s1 = w1s;            i1 = w1i;
      }
      if (lr == 0) {
        const int row = wm * 128 + mi * 16 + lg * 4 + r;
        uint2 e0; e0.x = __float_as_uint(s1); e0.y = (uint32_t)i1;
        uint2 e1; e1.x = __float_as_uint(s2); e1.y = (uint32_t)i2;
        mrg[(row * 4 + wn) * 2 + 0] = e0;
        mrg[(row * 4 + wn) * 2 + 1] = e1;
      }
    }
  }
  __syncthreads();

  if (tid < 256) {
    const int row = tid;
    float s1 = __builtin_inff(), s2 = __builtin_inff();
    int   i1 = KCODES, i2 = KCODES;
    const uint2* mp = mrg + row * 8;
#pragma unroll
    for (int t = 0; t < 8; ++t) {
      const float s = __uint_as_float(mp[t].x);
      const int   i = (int)mp[t].y;
      if (s < s1 || (s == s1 && i < i1)) { s2 = s1; i2 = i1; s1 = s; i1 = i; }
      else if (s < s2 || (s == s2 && i < i2)) { s2 = s; i2 = i; }
    }
    uint4 o;
    o.x = __float_as_uint(s1); o.y = (uint32_t)i1;
    o.z = __float_as_uint(s2); o.w = (uint32_t)i2;
    *((uint4*)(cand2 + ((size_t)(r0 + row) * 32 + nb) * 4)) = o;
  }
#undef STAGE
#undef LDFRAG
}

// ---------------------------------------------------------------------------
// K5: top-select + exact fp32 rescore. One wave per row; lane l holds 1 of 64
// (score,idx) pairs. Margin 48 covers fp8 coarse noise (>=5 sigma). Fast path
// when exactly one candidate in margin.
// ---------------------------------------------------------------------------
__global__ __launch_bounds__(256) void rescore_kernel(
    const float* __restrict__ x, const float* __restrict__ cb,
    const uint32_t* __restrict__ cand2, int* __restrict__ idx_ws,
    float* __restrict__ out) {
  const int row = blockIdx.x * 4 + (threadIdx.x >> 6);
  const int l = threadIdx.x & 63;
  if (row == 0 && l == 0) out[(size_t)MROWS * DDIM + MROWS] = 0.0f;

  const uint2 pr = ((const uint2*)(cand2 + (size_t)row * 128))[l];
  const float s = __uint_as_float(pr.x);
  const int   ci = (int)pr.y;

  float bs = s; int bi = ci;
#pragma unroll
  for (int off = 1; off < 64; off <<= 1) {
    const float os = __shfl_xor(bs, off, 64);
    const int   oi = __shfl_xor(bi, off, 64);
    if (os < bs || (os == bs && oi < bi)) { bs = os; bi = oi; }
  }
  const float thr = bs + 48.0f;
  unsigned long long m = __ballot(s <= thr);

  if (__popcll(m) == 1) {
    if (l == 0) {
      idx_ws[row] = bi;
      out[(size_t)MROWS * DDIM + row] = (float)bi;
    }
    return;
  }

  const float4* x4 = (const float4*)(x + (size_t)row * DDIM);
  float4 xv[4];
#pragma unroll
  for (int i = 0; i < 4; ++i) xv[i] = x4[i * 64 + l];

  float bestS = __builtin_inff(); int bestI = KCODES;
  while (m) {
    const int b = __builtin_ctzll(m);
    m &= m - 1;
    const int code = __shfl(ci, b, 64);
    const float4* c4 = (const float4*)(cb + (size_t)code * DDIM);
    float dot = 0.f, nn = 0.f;
#pragma unroll
    for (int i = 0; i < 4; ++i) {
      const float4 cv = c4[i * 64 + l];
      dot = fmaf(xv[i].x, cv.x, dot); dot = fmaf(xv[i].y, cv.y, dot);
      dot = fmaf(xv[i].z, cv.z, dot); dot = fmaf(xv[i].w, cv.w, dot);
      nn  = fmaf(cv.x, cv.x, nn);     nn  = fmaf(cv.y, cv.y, nn);
      nn  = fmaf(cv.z, cv.z, nn);     nn  = fmaf(cv.w, cv.w, nn);
    }
#pragma unroll
    for (int off = 32; off > 0; off >>= 1) {
      dot += __shfl_xor(dot, off, 64);
      nn  += __shfl_xor(nn,  off, 64);
    }
    const float sc = nn - 2.0f * dot;
    if (sc < bestS || (sc == bestS && code < bestI)) { bestS = sc; bestI = code; }
  }
  if (l == 0) {
    idx_ws[row] = bestI;
    out[(size_t)MROWS * DDIM + row] = (float)bestI;
  }
}

// ---------------------------------------------------------------------------
// K6/K7: bf16 GEMM C = A[M][K] * B[N][K]^T (+bias). EPI==1: relu->bf16.
// EPI==2: f32 store.
// ---------------------------------------------------------------------------
template <int EPI>
__global__ __launch_bounds__(256) void gemm_bt_kernel(
    const unsigned short* __restrict__ A, const unsigned short* __restrict__ B,
    const float* __restrict__ bias, void* __restrict__ outp,
    int Nsize, int Kred, int nblk) {
  __shared__ unsigned short As[128 * 32];
  __shared__ unsigned short Bs[128 * 32];
  const int tid = threadIdx.x;
  const int l = tid & 63, w = tid >> 6;
  const int lr = l & 15, lg = l >> 4;
  const int wm = w >> 1, wn = w & 1;
  const int mb = blockIdx.x / nblk, nb = blockIdx.x % nblk;
  const int r0 = mb * 128, c0 = nb * 128;
  const int prow = tid >> 2, pcol = (tid & 3) * 8;

  f32x4 acc[4][4];
#pragma unroll
  for (int mi = 0; mi < 4; ++mi)
#pragma unroll
    for (int ni = 0; ni < 4; ++ni) acc[mi][ni] = 0.0f;

  const size_t aoff0 = (size_t)(r0 + prow) * Kred + pcol;
  const size_t aoff1 = aoff0 + (size_t)64 * Kred;
  const size_t boff0 = (size_t)(c0 + prow) * Kred + pcol;
  const size_t boff1 = boff0 + (size_t)64 * Kred;

  const int nks = Kred >> 5;
  for (int ks = 0; ks < nks; ++ks) {
    const int k0 = ks * 32;
    gload_lds16(A + aoff0 + k0, &As[tid * 8]);
    gload_lds16(A + aoff1 + k0, &As[2048 + tid * 8]);
    gload_lds16(B + boff0 + k0, &Bs[tid * 8]);
    gload_lds16(B + boff1 + k0, &Bs[2048 + tid * 8]);
    __syncthreads();

    bf16x8 af[4], bfv[4];
#pragma unroll
    for (int mi = 0; mi < 4; ++mi)
      af[mi] = *reinterpret_cast<const bf16x8*>(
          &As[(wm * 64 + mi * 16 + lr) * 32 + lg * 8]);
#pragma unroll
    for (int ni = 0; ni < 4; ++ni)
      bfv[ni] = *reinterpret_cast<const bf16x8*>(
          &Bs[(wn * 64 + ni * 16 + lr) * 32 + lg * 8]);
#pragma unroll
    for (int mi = 0; mi < 4; ++mi)
#pragma unroll
      for (int ni = 0; ni < 4; ++ni)
        acc[mi][ni] = __builtin_amdgcn_mfma_f32_16x16x32_bf16(
            af[mi], bfv[ni], acc[mi][ni], 0, 0, 0);
    __syncthreads();
  }

#pragma unroll
  for (int ni = 0; ni < 4; ++ni) {
    const int col = c0 + wn * 64 + ni * 16 + lr;
    const float bv = bias[col];
#pragma unroll
    for (int mi = 0; mi < 4; ++mi) {
#pragma unroll
      for (int r = 0; r < 4; ++r) {
        const int row = r0 + wm * 64 + mi * 16 + lg * 4 + r;
        const float v = acc[mi][ni][r] + bv;
        if (EPI == 1) {
          ((unsigned short*)outp)[(size_t)row * Nsize + col] =
              f2bf(fmaxf(v, 0.0f));
        } else {
          ((float*)outp)[(size_t)row * Nsize + col] = v;
        }
      }
    }
  }
}

// ---------------------------------------------------------------------------
// K8: recon[row] = dec[idx[row]] gather-write + fused commitment loss.
// ---------------------------------------------------------------------------
__global__ __launch_bounds__(256) void epilogue_kernel(
    const float* __restrict__ x, const float* __restrict__ cb,
    const float* __restrict__ dec, const int* __restrict__ idx_ws,
    float* __restrict__ out) {
  __shared__ float wsum[4];
  const int r = blockIdx.x, t = threadIdx.x;
  const int code = idx_ws[r];
  const float4 dv = ((const float4*)(dec + (size_t)code * DDIM))[t];
  ((float4*)(out + (size_t)r * DDIM))[t] = dv;
  const float4 xv = ((const float4*)(x + (size_t)r * DDIM))[t];
  const float4 cv = ((const float4*)(cb + (size_t)code * DDIM))[t];
  const float ex = xv.x - cv.x, ey = xv.y - cv.y;
  const float ez = xv.z - cv.z, ew = xv.w - cv.w;
  float pr = ex * ex + ey * ey + ez * ez + ew * ew;
  pr = waveReduceSum(pr);
  if ((t & 63) == 0) wsum[t >> 6] = pr;
  __syncthreads();
  if (t == 0) {
    const float total = wsum[0] + wsum[1] + wsum[2] + wsum[3];
    atomicAdd(out + (size_t)MROWS * DDIM + MROWS, total * (0.25f / 16777216.0f));
  }
}

// ---------------------------------------------------------------------------
extern "C" void kernel_launch(void* const* d_in, const int* in_sizes, int n_in,
                              void* d_out, int out_size, void* d_ws,
                              size_t ws_size, hipStream_t stream) {
  const float* features = (const float*)d_in[0];  // [8,2048,1024]
  const float* codebook = (const float*)d_in[1];  // [8192,1024]
  const float* w1 = (const float*)d_in[2];        // [1024,512]
  const float* b1 = (const float*)d_in[3];        // [512]
  const float* w2 = (const float*)d_in[4];        // [512,1024]
  const float* b2 = (const float*)d_in[5];        // [1024]
  float* out = (float*)d_out;
  char* ws = (char*)d_ws;

  uint8_t*        xq8 = (uint8_t*)(ws + 0);                // 16,777,216
  uint8_t*        cq8 = (uint8_t*)(ws + 16777216);         //  8,388,608
  unsigned short* cbb = (unsigned short*)(ws + 25165824);  // 16,777,216
  float*          cn  = (float*)(ws + 41943040);           //     32,768
  unsigned short* w1t = (unsigned short*)(ws + 41975808);  //  1,048,576
  unsigned short* w2t = (unsigned short*)(ws + 43024384);  //  1,048,576
  unsigned short* hb  = (unsigned short*)(ws + 44072960);  //  8,388,608
  float*          dec = (float*)(ws + 52461568);           // 33,554,432
  int*            idxw = (int*)(ws + 86016000);            //     65,536
  // cand2 (8 MB) aliases dec: consumed by rescore BEFORE gemm<2> writes dec
  // (stream-ordered -> safe).
  uint32_t*       cand2 = (uint32_t*)(ws + 52461568);

  cvt_x_kernel<<<8192, 256, 0, stream>>>(features, xq8, MROWS * DDIM / 8);
  cvt_cb_cn_kernel<<<KCODES, 256, 0, stream>>>(codebook, cbb, cq8, cn);
  transpose_w_kernel<<<2048, 256, 0, stream>>>(w1, w1t, DDIM, HDIM);
  transpose_w_kernel<<<2048, 256, 0, stream>>>(w2, w2t, HDIM, DDIM);

  coarse_kernel<<<(MROWS / 256) * (KCODES / 256), 512, 0, stream>>>(
      xq8, cq8, cn, cand2);
  rescore_kernel<<<MROWS / 4, 256, 0, stream>>>(features, codebook, cand2,
                                                idxw, out);

  // decode the codebook (8192 rows), then recon = dec[idx]
  gemm_bt_kernel<1><<<64 * (HDIM / 128), 256, 0, stream>>>(
      cbb, w1t, b1, hb, HDIM, DDIM, HDIM / 128);
  gemm_bt_kernel<2><<<64 * (DDIM / 128), 256, 0, stream>>>(
      hb, w2t, b2, dec, DDIM, HDIM, DDIM / 128);

  epilogue_kernel<<<MROWS, 256, 0, stream>>>(features, codebook, dec, idxw, out);
}